// Round 13
// baseline (442.777 us; speedup 1.0000x reference)
//
#include <hip/hip_runtime.h>
#include <hip/hip_fp16.h>

#define NN 50000
#define NE 800000
#define NG 64
#define FD 64
#define BN_EPS 1e-5f
#define NBIN 98            // ceil(50000/512)
#define BINCAP 12288
#define SCH 4096
#define SCH_NBLK ((NE + SCH - 1) / SCH)          // 196
#define INV_NN (1.0f / NN)
#define MM_NODES 16
#define MMB_NBLK ((NN + MM_NODES - 1) / MM_NODES)  // 3125
#define G_NBLK ((NN + 3) / 4)                      // 12500
#define POOL_NBLK 512

// ---------------- CSR build: binned two-pass ----------------
__global__ __launch_bounds__(256) void k_binscatter(const int* __restrict__ row,
                                                    const int* __restrict__ col,
                                                    int* __restrict__ gcnt,
                                                    int* __restrict__ bins) {
    __shared__ int stage[SCH];
    __shared__ unsigned char stageb[SCH];
    __shared__ int cnt[NBIN], off[NBIN], cur[NBIN], gbase[NBIN];
    int t = threadIdx.x;
    int e0 = blockIdx.x * SCH;
    int nk = NE - e0; if (nk > SCH) nk = SCH;
    if (nk <= 0) return;
    for (int b = t; b < NBIN; b += 256) cnt[b] = 0;
    __syncthreads();
    for (int k = t; k < nk; k += 256) {
        int c = col[e0 + k];
        atomicAdd(&cnt[c >> 9], 1);
    }
    __syncthreads();
    if (t == 0) {
        int run = 0;
        for (int b = 0; b < NBIN; ++b) { off[b] = run; run += cnt[b]; }
    }
    __syncthreads();
    if (t < NBIN) {
        cur[t] = off[t];
        gbase[t] = t * BINCAP + atomicAdd(&gcnt[t], cnt[t]);
    }
    __syncthreads();
    for (int k = t; k < nk; k += 256) {
        int c = col[e0 + k];
        int r = row[e0 + k];
        int b = c >> 9;
        int pos = atomicAdd(&cur[b], 1);
        stage[pos] = ((c & 511) << 16) | r;
        stageb[pos] = (unsigned char)b;
    }
    __syncthreads();
    for (int k = t; k < nk; k += 256) {
        int b = stageb[k];
        bins[gbase[b] + (k - off[b])] = stage[k];
    }
}

// per-bin degree hist + in-block scan + dinv + xd; LAST block scans bin sums -> bofs, zeroes stats
__global__ __launch_bounds__(256) void k_binscan(const int* __restrict__ gcnt,
                                                 const int* __restrict__ bins,
                                                 const float* __restrict__ x,
                                                 int* __restrict__ cursor,
                                                 int* __restrict__ bsum,
                                                 int* __restrict__ bofs,
                                                 float* __restrict__ dinv,
                                                 float* __restrict__ xd,
                                                 int* __restrict__ ticket,
                                                 float* __restrict__ stats) {
    __shared__ int ldeg[512];
    __shared__ int psc[256];
    __shared__ int lastflag;
    int b = blockIdx.x, t = threadIdx.x;
    for (int l = t; l < 512; l += 256) ldeg[l] = 0;
    __syncthreads();
    int nb = gcnt[b];
    const int* bp = bins + b * BINCAP;
    for (int k = t; k < nb; k += 256) atomicAdd(&ldeg[bp[k] >> 16], 1);
    __syncthreads();
    int d0 = ldeg[2 * t], d1 = ldeg[2 * t + 1];
    int pv = d0 + d1;
    psc[t] = pv;
    __syncthreads();
    for (int off = 1; off < 256; off <<= 1) {
        int u = (t >= off) ? psc[t - off] : 0;
        __syncthreads();
        psc[t] += u;
        __syncthreads();
    }
    int excl = psc[t] - pv;
    int base = b << 9;
    int i0 = base + 2 * t, i1 = i0 + 1;
    if (i0 < NN) {
        cursor[i0] = excl;
        float dv = rsqrtf((float)d0 + 1.0f);
        dinv[i0] = dv; xd[i0] = x[i0] * dv;
    }
    if (i1 < NN) {
        cursor[i1] = excl + d0;
        float dv = rsqrtf((float)d1 + 1.0f);
        dinv[i1] = dv; xd[i1] = x[i1] * dv;
    }
    if (t == 255) bsum[b] = psc[255];
    // last-block-done: scan the 98 bin sums into exclusive offsets
    __threadfence();
    __syncthreads();
    if (t == 0) lastflag = (atomicAdd(ticket, 1) == NBIN - 1) ? 1 : 0;
    __syncthreads();
    if (lastflag) {
        __threadfence();
        if (t < 2) stats[t] = 0.0f;
        int v = (t < NBIN) ? bsum[t] : 0;
        psc[t] = v;
        __syncthreads();
        for (int off = 1; off < 256; off <<= 1) {
            int u = (t >= off) ? psc[t - off] : 0;
            __syncthreads();
            psc[t] += u;
            __syncthreads();
        }
        if (t < NBIN) bofs[t] = psc[t] - v;
    }
}

// per-bin fill of eidx (u16) + fused layer-1 scalar propagation + stats
__global__ __launch_bounds__(256) void k_binfill_l1(const int* __restrict__ gcnt,
                                                    const int* __restrict__ bins,
                                                    const int* __restrict__ cursor,
                                                    const int* __restrict__ bofs,
                                                    unsigned short* __restrict__ eidx,
                                                    const float* __restrict__ xd,
                                                    const float* __restrict__ x,
                                                    const float* __restrict__ dinv,
                                                    float* __restrict__ s,
                                                    float* __restrict__ stats) {
    __shared__ int lstart[512], lcur[512];
    __shared__ float ls[256], lq[256];
    int b = blockIdx.x, t = threadIdx.x;
    int base = b << 9;
    int bo = bofs[b];
    for (int l = t; l < 512; l += 256) {
        int i = base + l;
        int st = (i < NN) ? cursor[i] + bo : 0;
        lstart[l] = st; lcur[l] = st;
    }
    __syncthreads();
    int nb = gcnt[b];
    const int* bp = bins + b * BINCAP;
    for (int k = t; k < nb; k += 256) {
        int v = bp[k];
        int pos = atomicAdd(&lcur[v >> 16], 1);
        eidx[pos] = (unsigned short)(v & 0xFFFF);
    }
    __syncthreads();
    float a = 0.0f, q = 0.0f;
    #pragma unroll
    for (int half = 0; half < 2; ++half) {
        int l = t + half * 256;
        int i = base + l;
        if (i < NN) {
            float acc = 0.0f;
            int e0 = lstart[l], e1 = lcur[l];
            for (int k = e0; k < e1; ++k) acc += xd[eidx[k]];
            float di = dinv[i];
            float sv = di * (acc + di * x[i]);
            s[i] = sv;
            a += sv; q += sv * sv;
        }
    }
    ls[t] = a; lq[t] = q;
    __syncthreads();
    for (int st = 128; st > 0; st >>= 1) {
        if (t < st) { ls[t] += ls[t + st]; lq[t] += lq[t + st]; }
        __syncthreads();
    }
    if (t == 0) { atomicAdd(&stats[0], ls[0]); atomicAdd(&stats[1], lq[0]); }
}

// ---------------- fused coeffs + activation + 64x64 matmul (16 nodes/block, fp16 h'=h*dinv) ----------------
__global__ __launch_bounds__(256) void k_mm_l1(const float* __restrict__ s,
                                               const float* __restrict__ stats,
                                               const float* __restrict__ W1,
                                               const float* __restrict__ g1,
                                               const float* __restrict__ bt1,
                                               const float* __restrict__ W,
                                               const float* __restrict__ dinv,
                                               __half* __restrict__ h) {
    __shared__ float Ws[64 * 64];
    __shared__ float xs[4 * 64];
    __shared__ float als[64], cls[64];
    int t = threadIdx.x;
    for (int k = t; k < 64 * 64; k += 256) Ws[k] = W[k];
    if (t < 64) {
        float mean = stats[0] * INV_NN;
        float var  = stats[1] * INV_NN - mean * mean;
        float w = W1[t];
        float rinv = rsqrtf(var * w * w + BN_EPS);
        float a = g1[t] * w * rinv;
        als[t] = a;
        cls[t] = bt1[t] - a * mean;
    }
    int j = t & 63, n = t >> 6;
    #pragma unroll
    for (int it = 0; it < MM_NODES / 4; ++it) {
        int node = blockIdx.x * MM_NODES + it * 4 + n;
        float sv = (node < NN) ? s[node] : 0.0f;
        __syncthreads();
        xs[t] = fmaxf(als[j] * sv + cls[j], 0.0f);
        __syncthreads();
        if (node < NN) {
            float acc = 0.f;
            #pragma unroll
            for (int k = 0; k < 64; ++k) acc += xs[n * 64 + k] * Ws[k * 64 + j];
            h[node * 64 + j] = __float2half(acc * dinv[node]);
        }
    }
}

__global__ __launch_bounds__(256) void k_mm_bn(const float* __restrict__ src,
                                               const float* __restrict__ bnsum,
                                               const float* __restrict__ bnsq,
                                               const float* __restrict__ g,
                                               const float* __restrict__ bt,
                                               const float* __restrict__ W,
                                               const float* __restrict__ dinv,
                                               __half* __restrict__ h) {
    __shared__ float Ws[64 * 64];
    __shared__ float xs[4 * 64];
    __shared__ float scl[64], shf[64];
    int t = threadIdx.x;
    for (int k = t; k < 64 * 64; k += 256) Ws[k] = W[k];
    if (t < 64) {
        float mean = bnsum[t] * INV_NN;
        float var  = bnsq[t] * INV_NN - mean * mean;
        float rinv = rsqrtf(var + BN_EPS);
        float sc = g[t] * rinv;
        scl[t] = sc;
        shf[t] = bt[t] - sc * mean;
    }
    int j = t & 63, n = t >> 6;
    #pragma unroll
    for (int it = 0; it < MM_NODES / 4; ++it) {
        int node = blockIdx.x * MM_NODES + it * 4 + n;
        float v = (node < NN) ? src[node * 64 + j] : 0.0f;
        __syncthreads();
        xs[t] = fmaxf(scl[j] * v + shf[j], 0.0f);
        __syncthreads();
        if (node < NN) {
            float acc = 0.f;
            #pragma unroll
            for (int k = 0; k < 64; ++k) acc += xs[n * 64 + k] * Ws[k * 64 + j];
            h[node * 64 + j] = __float2half(acc * dinv[node]);
        }
    }
}

// ---------------- CSR gather aggregation ----------------
__global__ __launch_bounds__(256) void k_gather(const int* __restrict__ cursor,
                                                const int* __restrict__ bofs,
                                                const unsigned short* __restrict__ eidx,
                                                const float* __restrict__ dinv,
                                                const __half* __restrict__ h,
                                                const float* __restrict__ b,
                                                float* __restrict__ agg,
                                                float* __restrict__ bnsumz,
                                                float* __restrict__ bnsqz) {
    if (blockIdx.x == 0) {
        int tt = threadIdx.x;
        if (tt < 64) bnsumz[tt] = 0.0f;
        else if (tt < 128) bnsqz[tt - 64] = 0.0f;
    }
    int node = blockIdx.x * 4 + (threadIdx.x >> 6);
    if (node >= NN) return;
    int lane = threadIdx.x & 63;
    int eslot = lane >> 3;
    int fb = (lane & 7) << 3;
    int start = cursor[node] + bofs[node >> 9];
    int end = (node < NN - 1) ? cursor[node + 1] + bofs[(node + 1) >> 9] : NE;
    float a0 = 0.f, a1 = 0.f, a2 = 0.f, a3 = 0.f, a4 = 0.f, a5 = 0.f, a6 = 0.f, a7 = 0.f;
    float c0 = 0.f, c1 = 0.f, c2 = 0.f, c3 = 0.f, c4 = 0.f, c5 = 0.f, c6 = 0.f, c7 = 0.f;
    int e = start + eslot;
    for (; e + 8 < end; e += 16) {
        int r0 = eidx[e], r1 = eidx[e + 8];
        uint4 u = *reinterpret_cast<const uint4*>(&h[(r0 << 6) + fb]);
        uint4 v = *reinterpret_cast<const uint4*>(&h[(r1 << 6) + fb]);
        float2 p;
        p = __half22float2(*reinterpret_cast<__half2*>(&u.x)); a0 += p.x; a1 += p.y;
        p = __half22float2(*reinterpret_cast<__half2*>(&u.y)); a2 += p.x; a3 += p.y;
        p = __half22float2(*reinterpret_cast<__half2*>(&u.z)); a4 += p.x; a5 += p.y;
        p = __half22float2(*reinterpret_cast<__half2*>(&u.w)); a6 += p.x; a7 += p.y;
        p = __half22float2(*reinterpret_cast<__half2*>(&v.x)); c0 += p.x; c1 += p.y;
        p = __half22float2(*reinterpret_cast<__half2*>(&v.y)); c2 += p.x; c3 += p.y;
        p = __half22float2(*reinterpret_cast<__half2*>(&v.z)); c4 += p.x; c5 += p.y;
        p = __half22float2(*reinterpret_cast<__half2*>(&v.w)); c6 += p.x; c7 += p.y;
    }
    if (e < end) {
        int r = eidx[e];
        uint4 u = *reinterpret_cast<const uint4*>(&h[(r << 6) + fb]);
        float2 p;
        p = __half22float2(*reinterpret_cast<__half2*>(&u.x)); a0 += p.x; a1 += p.y;
        p = __half22float2(*reinterpret_cast<__half2*>(&u.y)); a2 += p.x; a3 += p.y;
        p = __half22float2(*reinterpret_cast<__half2*>(&u.z)); a4 += p.x; a5 += p.y;
        p = __half22float2(*reinterpret_cast<__half2*>(&u.w)); a6 += p.x; a7 += p.y;
    }
    a0 += c0; a1 += c1; a2 += c2; a3 += c3; a4 += c4; a5 += c5; a6 += c6; a7 += c7;
    #pragma unroll
    for (int d = 8; d <= 32; d <<= 1) {
        a0 += __shfl_xor(a0, d); a1 += __shfl_xor(a1, d);
        a2 += __shfl_xor(a2, d); a3 += __shfl_xor(a3, d);
        a4 += __shfl_xor(a4, d); a5 += __shfl_xor(a5, d);
        a6 += __shfl_xor(a6, d); a7 += __shfl_xor(a7, d);
    }
    if (eslot == 0) {
        float dc = dinv[node];
        uint4 u = *reinterpret_cast<const uint4*>(&h[(node << 6) + fb]);
        float2 p;
        p = __half22float2(*reinterpret_cast<__half2*>(&u.x)); a0 += p.x; a1 += p.y;
        p = __half22float2(*reinterpret_cast<__half2*>(&u.y)); a2 += p.x; a3 += p.y;
        p = __half22float2(*reinterpret_cast<__half2*>(&u.z)); a4 += p.x; a5 += p.y;
        p = __half22float2(*reinterpret_cast<__half2*>(&u.w)); a6 += p.x; a7 += p.y;
        const float4 bv0 = *reinterpret_cast<const float4*>(&b[fb]);
        const float4 bv1 = *reinterpret_cast<const float4*>(&b[fb + 4]);
        float4 o0, o1;
        o0.x = dc * a0 + bv0.x; o0.y = dc * a1 + bv0.y;
        o0.z = dc * a2 + bv0.z; o0.w = dc * a3 + bv0.w;
        o1.x = dc * a4 + bv1.x; o1.y = dc * a5 + bv1.y;
        o1.z = dc * a6 + bv1.z; o1.w = dc * a7 + bv1.w;
        *reinterpret_cast<float4*>(&agg[node * 64 + fb]) = o0;
        *reinterpret_cast<float4*>(&agg[node * 64 + fb + 4]) = o1;
    }
}

// ---------------- batchnorm stats (optionally zeros pooled/cnt) ----------------
__global__ __launch_bounds__(256) void k_bn_stats(const float* __restrict__ agg,
                                                  float* __restrict__ bnsum, float* __restrict__ bnsq,
                                                  float* __restrict__ pooledz, float* __restrict__ cntz) {
    if (pooledz != nullptr && blockIdx.x == 0) {
        for (int k = threadIdx.x; k < 64 * 64; k += 256) pooledz[k] = 0.0f;
        if (threadIdx.x < 64) cntz[threadIdx.x] = 0.0f;
    }
    __shared__ float ls[256], lq[256];
    int j = threadIdx.x & 63, nl = threadIdx.x >> 6;
    float a = 0.f, b = 0.f;
    for (int i = blockIdx.x * 4 + nl; i < NN; i += gridDim.x * 4) {
        float v = agg[i * 64 + j]; a += v; b += v * v;
    }
    ls[threadIdx.x] = a; lq[threadIdx.x] = b; __syncthreads();
    if (threadIdx.x < 128) { ls[threadIdx.x] += ls[threadIdx.x + 128]; lq[threadIdx.x] += lq[threadIdx.x + 128]; }
    __syncthreads();
    if (threadIdx.x < 64) {
        atomicAdd(&bnsum[j], ls[threadIdx.x] + ls[threadIdx.x + 64]);
        atomicAdd(&bnsq[j],  lq[threadIdx.x] + lq[threadIdx.x + 64]);
    }
}

// ---------------- fused BN-finalize + BN + pooling (segmented) + last-block FC ----------------
__global__ __launch_bounds__(256) void k_pool_bn_fc(const float* __restrict__ agg,
                                                    const float* __restrict__ bnsum,
                                                    const float* __restrict__ bnsq,
                                                    const float* __restrict__ g4,
                                                    const float* __restrict__ bt4,
                                                    const int* __restrict__ batch,
                                                    float* __restrict__ pooled,
                                                    float* __restrict__ cnt,
                                                    int* __restrict__ ticket,
                                                    const float* __restrict__ fw1,
                                                    const float* __restrict__ fb1,
                                                    const float* __restrict__ fw2,
                                                    const float* __restrict__ fb2,
                                                    float* __restrict__ out) {
    __shared__ int lastflag;
    const int wpb = 4;
    int wave = blockIdx.x * wpb + (threadIdx.x >> 6);
    int lane = threadIdx.x & 63;
    const int nwaves = gridDim.x * wpb;
    int chunk = (NN + nwaves - 1) / nwaves;
    int i0 = wave * chunk;
    int i1 = i0 + chunk; if (i1 > NN) i1 = NN;
    if (i0 < NN) {
        float mean = bnsum[lane] * INV_NN;
        float var  = bnsq[lane] * INV_NN - mean * mean;
        float rinv = rsqrtf(var + BN_EPS);
        float sc = g4[lane] * rinv;
        float sh = bt4[lane] - sc * mean;
        float acc = 0.0f;
        int curb = batch[i0];
        int runlen = 0;
        for (int i = i0; i < i1; ++i) {
            int b = batch[i];
            if (b != curb) {
                atomicAdd(&pooled[curb * 64 + lane], acc);
                if (lane == 0) atomicAdd(&cnt[curb], (float)runlen);
                acc = 0.0f; runlen = 0; curb = b;
            }
            acc += fmaxf(sc * agg[i * 64 + lane] + sh, 0.0f);
            ++runlen;
        }
        atomicAdd(&pooled[curb * 64 + lane], acc);
        if (lane == 0) atomicAdd(&cnt[curb], (float)runlen);
    }
    // last-block-done: FC head (2 graphs per iteration, 128 threads each)
    __threadfence();
    __syncthreads();
    if (threadIdx.x == 0) lastflag = (atomicAdd(ticket, 1) == (int)gridDim.x - 1) ? 1 : 0;
    __syncthreads();
    if (!lastflag) return;
    __threadfence();
    __shared__ float p[2][64], hsh[2][128];
    int half = threadIdx.x >> 7;    // 0 or 1
    int tt = threadIdx.x & 127;
    for (int it = 0; it < NG / 2; ++it) {
        int g = it * 2 + half;
        if (tt < 64) {
            float c = cnt[g]; c = c < 1.f ? 1.f : c;
            p[half][tt] = pooled[g * 64 + tt] / c;
        }
        __syncthreads();
        float acc = fb1[tt];
        #pragma unroll 8
        for (int k = 0; k < 64; ++k) acc += p[half][k] * fw1[tt * 64 + k];
        hsh[half][tt] = fmaxf(acc, 0.f);
        __syncthreads();
        if (tt < 10) {
            float o = fb2[tt];
            #pragma unroll 8
            for (int k = 0; k < 128; ++k) o += hsh[half][k] * fw2[tt * 128 + k];
            out[g * 10 + tt] = o;
        }
        __syncthreads();
    }
}

// ---------------- launch ----------------
extern "C" void kernel_launch(void* const* d_in, const int* in_sizes, int n_in,
                              void* d_out, int out_size, void* d_ws, size_t ws_size,
                              hipStream_t stream) {
    const float* x   = (const float*)d_in[0];
    const int* ei    = (const int*)d_in[1];
    const int* batch = (const int*)d_in[2];
    const float* W[5]  = {nullptr, (const float*)d_in[3],  (const float*)d_in[7],
                                   (const float*)d_in[11], (const float*)d_in[15]};
    const float* bb[5] = {nullptr, (const float*)d_in[4],  (const float*)d_in[8],
                                   (const float*)d_in[12], (const float*)d_in[16]};
    const float* gg[5] = {nullptr, (const float*)d_in[5],  (const float*)d_in[9],
                                   (const float*)d_in[13], (const float*)d_in[17]};
    const float* bt[5] = {nullptr, (const float*)d_in[6],  (const float*)d_in[10],
                                   (const float*)d_in[14], (const float*)d_in[18]};
    const float* fw1 = (const float*)d_in[19];
    const float* fb1 = (const float*)d_in[20];
    const float* fw2 = (const float*)d_in[21];
    const float* fb2 = (const float*)d_in[22];
    float* out = (float*)d_out;

    const int* row = ei;
    const int* col = ei + NE;

    float* ws = (float*)d_ws;
    int*   cursor  = (int*)ws;                    // N
    unsigned short* eidx = (unsigned short*)(ws + 50000);  // E u16
    float* dinv    = ws + 850000;                 // N
    float* xd      = ws + 900000;                 // N
    int*   bsum    = (int*)(ws + 950000);         // NBIN (inclusive per-bin sums)
    int*   bofs    = (int*)(ws + 950200);         // NBIN (exclusive offsets)
    float* s       = ws + 951000;                 // N
    float* stats   = ws + 1001008;                // 2
    float* bnsum   = ws + 1001072;                // 64
    float* bnsq    = ws + 1001136;                // 64
    float* pooled  = ws + 1001360;                // 64*64
    float* cnt     = ws + 1005456;                // 64
    int*   gcnt    = (int*)(ws + 1056000);        // NBIN + ticket0 + ticket1
    int*   ticket0 = gcnt + NBIN;
    int*   ticket1 = gcnt + NBIN + 1;
    __half* hbuf   = (__half*)(ws + 1100000);     // N*64 halves (bins alias pre-layer2)
    int*   bins    = (int*)(ws + 1100000);        // NBIN*BINCAP ints
    float* aggbuf  = ws + 4300000;                // N*64

    const int B = 256;

    // CSR build (binned) + dinv + xd  (gcnt + tickets zeroed together)
    hipMemsetAsync(gcnt, 0, (NBIN + 2) * sizeof(int), stream);
    k_binscatter<<<SCH_NBLK, B, 0, stream>>>(row, col, gcnt, bins);
    k_binscan<<<NBIN, B, 0, stream>>>(gcnt, bins, x, cursor, bsum, bofs, dinv, xd, ticket0, stats);
    // fill eidx (u16) + layer-1 scalar propagation + stats
    k_binfill_l1<<<NBIN, B, 0, stream>>>(gcnt, bins, cursor, bofs, eidx, xd, x, dinv, s, stats);

    // layer 2
    k_mm_l1<<<MMB_NBLK, B, 0, stream>>>(s, stats, W[1], gg[1], bt[1], W[2], dinv, hbuf);
    k_gather<<<G_NBLK, B, 0, stream>>>(cursor, bofs, eidx, dinv, hbuf, bb[2], aggbuf, bnsum, bnsq);
    k_bn_stats<<<512, B, 0, stream>>>(aggbuf, bnsum, bnsq, nullptr, nullptr);

    // layers 3,4
    for (int L = 3; L <= 4; ++L) {
        k_mm_bn<<<MMB_NBLK, B, 0, stream>>>(aggbuf, bnsum, bnsq, gg[L - 1], bt[L - 1], W[L], dinv, hbuf);
        k_gather<<<G_NBLK, B, 0, stream>>>(cursor, bofs, eidx, dinv, hbuf, bb[L], aggbuf, bnsum, bnsq);
        k_bn_stats<<<512, B, 0, stream>>>(aggbuf, bnsum, bnsq,
                                          (L == 4) ? pooled : nullptr, (L == 4) ? cnt : nullptr);
    }

    // fused finalize+BN+pool (segmented) + last-block FC
    k_pool_bn_fc<<<POOL_NBLK, B, 0, stream>>>(aggbuf, bnsum, bnsq, gg[4], bt[4], batch,
                                              pooled, cnt, ticket1, fw1, fb1, fw2, fb2, out);
}

// Round 14
// 302.617 us; speedup vs baseline: 1.4632x; 1.4632x over previous
//
#include <hip/hip_runtime.h>
#include <hip/hip_fp16.h>

#define NN 50000
#define NE 800000
#define NG 64
#define FD 64
#define BN_EPS 1e-5f
#define NBIN 98            // ceil(50000/512)
#define BINCAP 12288
#define SCH 4096
#define SCH_NBLK ((NE + SCH - 1) / SCH)          // 196
#define INV_NN (1.0f / NN)
#define MM_NODES 16
#define MMB_NBLK ((NN + MM_NODES - 1) / MM_NODES)  // 3125
#define G_NBLK ((NN + 3) / 4)                      // 12500

// ---------------- CSR build: binned two-pass ----------------
__global__ __launch_bounds__(256) void k_binscatter(const int* __restrict__ row,
                                                    const int* __restrict__ col,
                                                    int* __restrict__ gcnt,
                                                    int* __restrict__ bins) {
    __shared__ int stage[SCH];
    __shared__ unsigned char stageb[SCH];
    __shared__ int cnt[NBIN], off[NBIN], cur[NBIN], gbase[NBIN];
    int t = threadIdx.x;
    int e0 = blockIdx.x * SCH;
    int nk = NE - e0; if (nk > SCH) nk = SCH;
    if (nk <= 0) return;
    for (int b = t; b < NBIN; b += 256) cnt[b] = 0;
    __syncthreads();
    for (int k = t; k < nk; k += 256) {
        int c = col[e0 + k];
        atomicAdd(&cnt[c >> 9], 1);
    }
    __syncthreads();
    if (t == 0) {
        int run = 0;
        for (int b = 0; b < NBIN; ++b) { off[b] = run; run += cnt[b]; }
    }
    __syncthreads();
    if (t < NBIN) {
        cur[t] = off[t];
        gbase[t] = t * BINCAP + atomicAdd(&gcnt[t], cnt[t]);
    }
    __syncthreads();
    for (int k = t; k < nk; k += 256) {
        int c = col[e0 + k];
        int r = row[e0 + k];
        int b = c >> 9;
        int pos = atomicAdd(&cur[b], 1);
        stage[pos] = ((c & 511) << 16) | r;
        stageb[pos] = (unsigned char)b;
    }
    __syncthreads();
    for (int k = t; k < nk; k += 256) {
        int b = stageb[k];
        bins[gbase[b] + (k - off[b])] = stage[k];
    }
}

// per-bin degree hist + in-block scan + dinv + xd; LAST block scans bin sums -> bofs, zeroes stats
__global__ __launch_bounds__(256) void k_binscan(const int* __restrict__ gcnt,
                                                 const int* __restrict__ bins,
                                                 const float* __restrict__ x,
                                                 int* __restrict__ cursor,
                                                 int* __restrict__ bsum,
                                                 int* __restrict__ bofs,
                                                 float* __restrict__ dinv,
                                                 float* __restrict__ xd,
                                                 int* __restrict__ ticket,
                                                 float* __restrict__ stats) {
    __shared__ int ldeg[512];
    __shared__ int psc[256];
    __shared__ int lastflag;
    int b = blockIdx.x, t = threadIdx.x;
    for (int l = t; l < 512; l += 256) ldeg[l] = 0;
    __syncthreads();
    int nb = gcnt[b];
    const int* bp = bins + b * BINCAP;
    for (int k = t; k < nb; k += 256) atomicAdd(&ldeg[bp[k] >> 16], 1);
    __syncthreads();
    int d0 = ldeg[2 * t], d1 = ldeg[2 * t + 1];
    int pv = d0 + d1;
    psc[t] = pv;
    __syncthreads();
    for (int off = 1; off < 256; off <<= 1) {
        int u = (t >= off) ? psc[t - off] : 0;
        __syncthreads();
        psc[t] += u;
        __syncthreads();
    }
    int excl = psc[t] - pv;
    int base = b << 9;
    int i0 = base + 2 * t, i1 = i0 + 1;
    if (i0 < NN) {
        cursor[i0] = excl;
        float dv = rsqrtf((float)d0 + 1.0f);
        dinv[i0] = dv; xd[i0] = x[i0] * dv;
    }
    if (i1 < NN) {
        cursor[i1] = excl + d0;
        float dv = rsqrtf((float)d1 + 1.0f);
        dinv[i1] = dv; xd[i1] = x[i1] * dv;
    }
    if (t == 255) bsum[b] = psc[255];
    // last-block-done: scan the 98 bin sums into exclusive offsets
    __threadfence();
    __syncthreads();
    if (t == 0) lastflag = (atomicAdd(ticket, 1) == NBIN - 1) ? 1 : 0;
    __syncthreads();
    if (lastflag) {
        __threadfence();
        if (t < 2) stats[t] = 0.0f;
        int v = (t < NBIN) ? bsum[t] : 0;
        psc[t] = v;
        __syncthreads();
        for (int off = 1; off < 256; off <<= 1) {
            int u = (t >= off) ? psc[t - off] : 0;
            __syncthreads();
            psc[t] += u;
            __syncthreads();
        }
        if (t < NBIN) bofs[t] = psc[t] - v;
    }
}

// per-bin fill of eidx (u16) + fused layer-1 scalar propagation + stats
__global__ __launch_bounds__(256) void k_binfill_l1(const int* __restrict__ gcnt,
                                                    const int* __restrict__ bins,
                                                    const int* __restrict__ cursor,
                                                    const int* __restrict__ bofs,
                                                    unsigned short* __restrict__ eidx,
                                                    const float* __restrict__ xd,
                                                    const float* __restrict__ x,
                                                    const float* __restrict__ dinv,
                                                    float* __restrict__ s,
                                                    float* __restrict__ stats) {
    __shared__ int lstart[512], lcur[512];
    __shared__ float ls[256], lq[256];
    int b = blockIdx.x, t = threadIdx.x;
    int base = b << 9;
    int bo = bofs[b];
    for (int l = t; l < 512; l += 256) {
        int i = base + l;
        int st = (i < NN) ? cursor[i] + bo : 0;
        lstart[l] = st; lcur[l] = st;
    }
    __syncthreads();
    int nb = gcnt[b];
    const int* bp = bins + b * BINCAP;
    for (int k = t; k < nb; k += 256) {
        int v = bp[k];
        int pos = atomicAdd(&lcur[v >> 16], 1);
        eidx[pos] = (unsigned short)(v & 0xFFFF);
    }
    __syncthreads();
    float a = 0.0f, q = 0.0f;
    #pragma unroll
    for (int half = 0; half < 2; ++half) {
        int l = t + half * 256;
        int i = base + l;
        if (i < NN) {
            float acc = 0.0f;
            int e0 = lstart[l], e1 = lcur[l];
            for (int k = e0; k < e1; ++k) acc += xd[eidx[k]];
            float di = dinv[i];
            float sv = di * (acc + di * x[i]);
            s[i] = sv;
            a += sv; q += sv * sv;
        }
    }
    ls[t] = a; lq[t] = q;
    __syncthreads();
    for (int st = 128; st > 0; st >>= 1) {
        if (t < st) { ls[t] += ls[t + st]; lq[t] += lq[t + st]; }
        __syncthreads();
    }
    if (t == 0) { atomicAdd(&stats[0], ls[0]); atomicAdd(&stats[1], lq[0]); }
}

// ---------------- fused coeffs + activation + 64x64 matmul (16 nodes/block, fp16 h'=h*dinv) ----------------
__global__ __launch_bounds__(256) void k_mm_l1(const float* __restrict__ s,
                                               const float* __restrict__ stats,
                                               const float* __restrict__ W1,
                                               const float* __restrict__ g1,
                                               const float* __restrict__ bt1,
                                               const float* __restrict__ W,
                                               const float* __restrict__ dinv,
                                               __half* __restrict__ h) {
    __shared__ float Ws[64 * 64];
    __shared__ float xs[4 * 64];
    __shared__ float als[64], cls[64];
    int t = threadIdx.x;
    for (int k = t; k < 64 * 64; k += 256) Ws[k] = W[k];
    if (t < 64) {
        float mean = stats[0] * INV_NN;
        float var  = stats[1] * INV_NN - mean * mean;
        float w = W1[t];
        float rinv = rsqrtf(var * w * w + BN_EPS);
        float a = g1[t] * w * rinv;
        als[t] = a;
        cls[t] = bt1[t] - a * mean;
    }
    int j = t & 63, n = t >> 6;
    #pragma unroll
    for (int it = 0; it < MM_NODES / 4; ++it) {
        int node = blockIdx.x * MM_NODES + it * 4 + n;
        float sv = (node < NN) ? s[node] : 0.0f;
        __syncthreads();
        xs[t] = fmaxf(als[j] * sv + cls[j], 0.0f);
        __syncthreads();
        if (node < NN) {
            float acc = 0.f;
            #pragma unroll
            for (int k = 0; k < 64; ++k) acc += xs[n * 64 + k] * Ws[k * 64 + j];
            h[node * 64 + j] = __float2half(acc * dinv[node]);
        }
    }
}

__global__ __launch_bounds__(256) void k_mm_bn(const float* __restrict__ src,
                                               const float* __restrict__ bnsum,
                                               const float* __restrict__ bnsq,
                                               const float* __restrict__ g,
                                               const float* __restrict__ bt,
                                               const float* __restrict__ W,
                                               const float* __restrict__ dinv,
                                               __half* __restrict__ h) {
    __shared__ float Ws[64 * 64];
    __shared__ float xs[4 * 64];
    __shared__ float scl[64], shf[64];
    int t = threadIdx.x;
    for (int k = t; k < 64 * 64; k += 256) Ws[k] = W[k];
    if (t < 64) {
        float mean = bnsum[t] * INV_NN;
        float var  = bnsq[t] * INV_NN - mean * mean;
        float rinv = rsqrtf(var + BN_EPS);
        float sc = g[t] * rinv;
        scl[t] = sc;
        shf[t] = bt[t] - sc * mean;
    }
    int j = t & 63, n = t >> 6;
    #pragma unroll
    for (int it = 0; it < MM_NODES / 4; ++it) {
        int node = blockIdx.x * MM_NODES + it * 4 + n;
        float v = (node < NN) ? src[node * 64 + j] : 0.0f;
        __syncthreads();
        xs[t] = fmaxf(scl[j] * v + shf[j], 0.0f);
        __syncthreads();
        if (node < NN) {
            float acc = 0.f;
            #pragma unroll
            for (int k = 0; k < 64; ++k) acc += xs[n * 64 + k] * Ws[k * 64 + j];
            h[node * 64 + j] = __float2half(acc * dinv[node]);
        }
    }
}

// ---------------- CSR gather aggregation ----------------
// h is pre-scaled by dinv[src]; agg[c] = dinv[c]*(sum_r h'[r] + h'[c]) + b
__global__ __launch_bounds__(256) void k_gather(const int* __restrict__ cursor,
                                                const int* __restrict__ bofs,
                                                const unsigned short* __restrict__ eidx,
                                                const float* __restrict__ dinv,
                                                const __half* __restrict__ h,
                                                const float* __restrict__ b,
                                                float* __restrict__ agg,
                                                float* __restrict__ bnsumz,
                                                float* __restrict__ bnsqz) {
    if (blockIdx.x == 0) {
        int tt = threadIdx.x;
        if (tt < 64) bnsumz[tt] = 0.0f;
        else if (tt < 128) bnsqz[tt - 64] = 0.0f;
    }
    int node = blockIdx.x * 4 + (threadIdx.x >> 6);
    if (node >= NN) return;
    int lane = threadIdx.x & 63;
    int eslot = lane >> 3;
    int fb = (lane & 7) << 3;
    int start = cursor[node] + bofs[node >> 9];
    int end = (node < NN - 1) ? cursor[node + 1] + bofs[(node + 1) >> 9] : NE;
    float a0 = 0.f, a1 = 0.f, a2 = 0.f, a3 = 0.f, a4 = 0.f, a5 = 0.f, a6 = 0.f, a7 = 0.f;
    float c0 = 0.f, c1 = 0.f, c2 = 0.f, c3 = 0.f, c4 = 0.f, c5 = 0.f, c6 = 0.f, c7 = 0.f;
    int e = start + eslot;
    for (; e + 8 < end; e += 16) {
        int r0 = eidx[e], r1 = eidx[e + 8];
        uint4 u = *reinterpret_cast<const uint4*>(&h[(r0 << 6) + fb]);
        uint4 v = *reinterpret_cast<const uint4*>(&h[(r1 << 6) + fb]);
        float2 p;
        p = __half22float2(*reinterpret_cast<__half2*>(&u.x)); a0 += p.x; a1 += p.y;
        p = __half22float2(*reinterpret_cast<__half2*>(&u.y)); a2 += p.x; a3 += p.y;
        p = __half22float2(*reinterpret_cast<__half2*>(&u.z)); a4 += p.x; a5 += p.y;
        p = __half22float2(*reinterpret_cast<__half2*>(&u.w)); a6 += p.x; a7 += p.y;
        p = __half22float2(*reinterpret_cast<__half2*>(&v.x)); c0 += p.x; c1 += p.y;
        p = __half22float2(*reinterpret_cast<__half2*>(&v.y)); c2 += p.x; c3 += p.y;
        p = __half22float2(*reinterpret_cast<__half2*>(&v.z)); c4 += p.x; c5 += p.y;
        p = __half22float2(*reinterpret_cast<__half2*>(&v.w)); c6 += p.x; c7 += p.y;
    }
    if (e < end) {
        int r = eidx[e];
        uint4 u = *reinterpret_cast<const uint4*>(&h[(r << 6) + fb]);
        float2 p;
        p = __half22float2(*reinterpret_cast<__half2*>(&u.x)); a0 += p.x; a1 += p.y;
        p = __half22float2(*reinterpret_cast<__half2*>(&u.y)); a2 += p.x; a3 += p.y;
        p = __half22float2(*reinterpret_cast<__half2*>(&u.z)); a4 += p.x; a5 += p.y;
        p = __half22float2(*reinterpret_cast<__half2*>(&u.w)); a6 += p.x; a7 += p.y;
    }
    a0 += c0; a1 += c1; a2 += c2; a3 += c3; a4 += c4; a5 += c5; a6 += c6; a7 += c7;
    #pragma unroll
    for (int d = 8; d <= 32; d <<= 1) {
        a0 += __shfl_xor(a0, d); a1 += __shfl_xor(a1, d);
        a2 += __shfl_xor(a2, d); a3 += __shfl_xor(a3, d);
        a4 += __shfl_xor(a4, d); a5 += __shfl_xor(a5, d);
        a6 += __shfl_xor(a6, d); a7 += __shfl_xor(a7, d);
    }
    if (eslot == 0) {
        float dc = dinv[node];
        uint4 u = *reinterpret_cast<const uint4*>(&h[(node << 6) + fb]);
        float2 p;
        p = __half22float2(*reinterpret_cast<__half2*>(&u.x)); a0 += p.x; a1 += p.y;
        p = __half22float2(*reinterpret_cast<__half2*>(&u.y)); a2 += p.x; a3 += p.y;
        p = __half22float2(*reinterpret_cast<__half2*>(&u.z)); a4 += p.x; a5 += p.y;
        p = __half22float2(*reinterpret_cast<__half2*>(&u.w)); a6 += p.x; a7 += p.y;
        const float4 bv0 = *reinterpret_cast<const float4*>(&b[fb]);
        const float4 bv1 = *reinterpret_cast<const float4*>(&b[fb + 4]);
        float4 o0, o1;
        o0.x = dc * a0 + bv0.x; o0.y = dc * a1 + bv0.y;
        o0.z = dc * a2 + bv0.z; o0.w = dc * a3 + bv0.w;
        o1.x = dc * a4 + bv1.x; o1.y = dc * a5 + bv1.y;
        o1.z = dc * a6 + bv1.z; o1.w = dc * a7 + bv1.w;
        *reinterpret_cast<float4*>(&agg[node * 64 + fb]) = o0;
        *reinterpret_cast<float4*>(&agg[node * 64 + fb + 4]) = o1;
    }
}

// ---------------- batchnorm stats (optionally zeros pooled/cnt) ----------------
__global__ __launch_bounds__(256) void k_bn_stats(const float* __restrict__ agg,
                                                  float* __restrict__ bnsum, float* __restrict__ bnsq,
                                                  float* __restrict__ pooledz, float* __restrict__ cntz) {
    if (pooledz != nullptr && blockIdx.x == 0) {
        for (int k = threadIdx.x; k < 64 * 64; k += 256) pooledz[k] = 0.0f;
        if (threadIdx.x < 64) cntz[threadIdx.x] = 0.0f;
    }
    __shared__ float ls[256], lq[256];
    int j = threadIdx.x & 63, nl = threadIdx.x >> 6;
    float a = 0.f, b = 0.f;
    for (int i = blockIdx.x * 4 + nl; i < NN; i += gridDim.x * 4) {
        float v = agg[i * 64 + j]; a += v; b += v * v;
    }
    ls[threadIdx.x] = a; lq[threadIdx.x] = b; __syncthreads();
    if (threadIdx.x < 128) { ls[threadIdx.x] += ls[threadIdx.x + 128]; lq[threadIdx.x] += lq[threadIdx.x + 128]; }
    __syncthreads();
    if (threadIdx.x < 64) {
        atomicAdd(&bnsum[j], ls[threadIdx.x] + ls[threadIdx.x + 64]);
        atomicAdd(&bnsq[j],  lq[threadIdx.x] + lq[threadIdx.x + 64]);
    }
}

// ---------------- fused BN-finalize + BN + pooling (segmented) ----------------
__global__ __launch_bounds__(256) void k_pool_bn(const float* __restrict__ agg,
                                                 const float* __restrict__ bnsum,
                                                 const float* __restrict__ bnsq,
                                                 const float* __restrict__ g4,
                                                 const float* __restrict__ bt4,
                                                 const int* __restrict__ batch,
                                                 float* __restrict__ pooled,
                                                 float* __restrict__ cnt) {
    const int wpb = 4;
    int wave = blockIdx.x * wpb + (threadIdx.x >> 6);
    int lane = threadIdx.x & 63;
    const int nwaves = gridDim.x * wpb;
    int chunk = (NN + nwaves - 1) / nwaves;
    int i0 = wave * chunk;
    int i1 = i0 + chunk; if (i1 > NN) i1 = NN;
    if (i0 >= NN) return;
    float mean = bnsum[lane] * INV_NN;
    float var  = bnsq[lane] * INV_NN - mean * mean;
    float rinv = rsqrtf(var + BN_EPS);
    float sc = g4[lane] * rinv;
    float sh = bt4[lane] - sc * mean;
    float acc = 0.0f;
    int curb = batch[i0];
    int runlen = 0;
    for (int i = i0; i < i1; ++i) {
        int b = batch[i];
        if (b != curb) {
            atomicAdd(&pooled[curb * 64 + lane], acc);
            if (lane == 0) atomicAdd(&cnt[curb], (float)runlen);
            acc = 0.0f; runlen = 0; curb = b;
        }
        acc += fmaxf(sc * agg[i * 64 + lane] + sh, 0.0f);
        ++runlen;
    }
    atomicAdd(&pooled[curb * 64 + lane], acc);
    if (lane == 0) atomicAdd(&cnt[curb], (float)runlen);
}

__global__ __launch_bounds__(128) void k_fc(const float* __restrict__ pooled, const float* __restrict__ cnt,
                                            const float* __restrict__ fw1, const float* __restrict__ fb1,
                                            const float* __restrict__ fw2, const float* __restrict__ fb2,
                                            float* __restrict__ out) {
    __shared__ float p[64], hsh[128];
    int g = blockIdx.x, t = threadIdx.x;
    if (t < 64) {
        float c = cnt[g]; c = c < 1.f ? 1.f : c;
        p[t] = pooled[g * 64 + t] / c;
    }
    __syncthreads();
    float acc = fb1[t];
    #pragma unroll 8
    for (int k = 0; k < 64; ++k) acc += p[k] * fw1[t * 64 + k];
    hsh[t] = fmaxf(acc, 0.f);
    __syncthreads();
    if (t < 10) {
        float o = fb2[t];
        #pragma unroll 8
        for (int k = 0; k < 128; ++k) o += hsh[k] * fw2[t * 128 + k];
        out[g * 10 + t] = o;
    }
}

// ---------------- launch ----------------
extern "C" void kernel_launch(void* const* d_in, const int* in_sizes, int n_in,
                              void* d_out, int out_size, void* d_ws, size_t ws_size,
                              hipStream_t stream) {
    const float* x   = (const float*)d_in[0];
    const int* ei    = (const int*)d_in[1];
    const int* batch = (const int*)d_in[2];
    const float* W[5]  = {nullptr, (const float*)d_in[3],  (const float*)d_in[7],
                                   (const float*)d_in[11], (const float*)d_in[15]};
    const float* bb[5] = {nullptr, (const float*)d_in[4],  (const float*)d_in[8],
                                   (const float*)d_in[12], (const float*)d_in[16]};
    const float* gg[5] = {nullptr, (const float*)d_in[5],  (const float*)d_in[9],
                                   (const float*)d_in[13], (const float*)d_in[17]};
    const float* bt[5] = {nullptr, (const float*)d_in[6],  (const float*)d_in[10],
                                   (const float*)d_in[14], (const float*)d_in[18]};
    const float* fw1 = (const float*)d_in[19];
    const float* fb1 = (const float*)d_in[20];
    const float* fw2 = (const float*)d_in[21];
    const float* fb2 = (const float*)d_in[22];
    float* out = (float*)d_out;

    const int* row = ei;
    const int* col = ei + NE;

    float* ws = (float*)d_ws;
    int*   cursor  = (int*)ws;                    // N
    unsigned short* eidx = (unsigned short*)(ws + 50000);  // E u16
    float* dinv    = ws + 850000;                 // N
    float* xd      = ws + 900000;                 // N
    int*   bsum    = (int*)(ws + 950000);         // NBIN (inclusive per-bin sums)
    int*   bofs    = (int*)(ws + 950200);         // NBIN (exclusive offsets)
    float* s       = ws + 951000;                 // N
    float* stats   = ws + 1001008;                // 2
    float* bnsum   = ws + 1001072;                // 64
    float* bnsq    = ws + 1001136;                // 64
    float* pooled  = ws + 1001360;                // 64*64
    float* cnt     = ws + 1005456;                // 64
    int*   gcnt    = (int*)(ws + 1056000);        // NBIN + ticket0
    int*   ticket0 = gcnt + NBIN;
    __half* hbuf   = (__half*)(ws + 1100000);     // N*64 halves (bins alias pre-layer2)
    int*   bins    = (int*)(ws + 1100000);        // NBIN*BINCAP ints
    float* aggbuf  = ws + 4300000;                // N*64

    const int B = 256;

    // CSR build (binned) + dinv + xd  (gcnt + ticket zeroed together)
    hipMemsetAsync(gcnt, 0, (NBIN + 1) * sizeof(int), stream);
    k_binscatter<<<SCH_NBLK, B, 0, stream>>>(row, col, gcnt, bins);
    k_binscan<<<NBIN, B, 0, stream>>>(gcnt, bins, x, cursor, bsum, bofs, dinv, xd, ticket0, stats);
    // fill eidx (u16) + layer-1 scalar propagation + stats
    k_binfill_l1<<<NBIN, B, 0, stream>>>(gcnt, bins, cursor, bofs, eidx, xd, x, dinv, s, stats);

    // layer 2
    k_mm_l1<<<MMB_NBLK, B, 0, stream>>>(s, stats, W[1], gg[1], bt[1], W[2], dinv, hbuf);
    k_gather<<<G_NBLK, B, 0, stream>>>(cursor, bofs, eidx, dinv, hbuf, bb[2], aggbuf, bnsum, bnsq);
    k_bn_stats<<<512, B, 0, stream>>>(aggbuf, bnsum, bnsq, nullptr, nullptr);

    // layers 3,4
    for (int L = 3; L <= 4; ++L) {
        k_mm_bn<<<MMB_NBLK, B, 0, stream>>>(aggbuf, bnsum, bnsq, gg[L - 1], bt[L - 1], W[L], dinv, hbuf);
        k_gather<<<G_NBLK, B, 0, stream>>>(cursor, bofs, eidx, dinv, hbuf, bb[L], aggbuf, bnsum, bnsq);
        k_bn_stats<<<512, B, 0, stream>>>(aggbuf, bnsum, bnsq,
                                          (L == 4) ? pooled : nullptr, (L == 4) ? cnt : nullptr);
    }

    // fused finalize+BN+pool (segmented) + FC
    k_pool_bn<<<512, B, 0, stream>>>(aggbuf, bnsum, bnsq, gg[4], bt[4], batch, pooled, cnt);
    k_fc<<<NG, 128, 0, stream>>>(pooled, cnt, fw1, fb1, fw2, fb2, out);
}

// Round 15
// 299.019 us; speedup vs baseline: 1.4808x; 1.0120x over previous
//
#include <hip/hip_runtime.h>
#include <hip/hip_fp16.h>

#define NN 50000
#define NE 800000
#define NG 64
#define FD 64
#define BN_EPS 1e-5f
#define NBIN 98            // ceil(50000/512)
#define BINCAP 12288
#define SCH 4096
#define SCH_NBLK ((NE + SCH - 1) / SCH)          // 196
#define INV_NN (1.0f / NN)
#define MM_NODES 16
#define MMB_NBLK ((NN + MM_NODES - 1) / MM_NODES)  // 3125
#define G2_NBLK (NN / 8)                           // 6250 (NN % 8 == 0)

// ---------------- CSR build: binned two-pass ----------------
__global__ __launch_bounds__(256) void k_binscatter(const int* __restrict__ row,
                                                    const int* __restrict__ col,
                                                    int* __restrict__ gcnt,
                                                    int* __restrict__ bins) {
    __shared__ int stage[SCH];
    __shared__ unsigned char stageb[SCH];
    __shared__ int cnt[NBIN], off[NBIN], cur[NBIN], gbase[NBIN];
    int t = threadIdx.x;
    int e0 = blockIdx.x * SCH;
    int nk = NE - e0; if (nk > SCH) nk = SCH;
    if (nk <= 0) return;
    for (int b = t; b < NBIN; b += 256) cnt[b] = 0;
    __syncthreads();
    for (int k = t; k < nk; k += 256) {
        int c = col[e0 + k];
        atomicAdd(&cnt[c >> 9], 1);
    }
    __syncthreads();
    if (t == 0) {
        int run = 0;
        for (int b = 0; b < NBIN; ++b) { off[b] = run; run += cnt[b]; }
    }
    __syncthreads();
    if (t < NBIN) {
        cur[t] = off[t];
        gbase[t] = t * BINCAP + atomicAdd(&gcnt[t], cnt[t]);
    }
    __syncthreads();
    for (int k = t; k < nk; k += 256) {
        int c = col[e0 + k];
        int r = row[e0 + k];
        int b = c >> 9;
        int pos = atomicAdd(&cur[b], 1);
        stage[pos] = ((c & 511) << 16) | r;
        stageb[pos] = (unsigned char)b;
    }
    __syncthreads();
    for (int k = t; k < nk; k += 256) {
        int b = stageb[k];
        bins[gbase[b] + (k - off[b])] = stage[k];
    }
}

// per-bin degree hist + in-block scan + dinv + xd; LAST block scans bin sums -> bofs, zeroes stats
__global__ __launch_bounds__(256) void k_binscan(const int* __restrict__ gcnt,
                                                 const int* __restrict__ bins,
                                                 const float* __restrict__ x,
                                                 int* __restrict__ cursor,
                                                 int* __restrict__ bsum,
                                                 int* __restrict__ bofs,
                                                 float* __restrict__ dinv,
                                                 float* __restrict__ xd,
                                                 int* __restrict__ ticket,
                                                 float* __restrict__ stats) {
    __shared__ int ldeg[512];
    __shared__ int psc[256];
    __shared__ int lastflag;
    int b = blockIdx.x, t = threadIdx.x;
    for (int l = t; l < 512; l += 256) ldeg[l] = 0;
    __syncthreads();
    int nb = gcnt[b];
    const int* bp = bins + b * BINCAP;
    for (int k = t; k < nb; k += 256) atomicAdd(&ldeg[bp[k] >> 16], 1);
    __syncthreads();
    int d0 = ldeg[2 * t], d1 = ldeg[2 * t + 1];
    int pv = d0 + d1;
    psc[t] = pv;
    __syncthreads();
    for (int off = 1; off < 256; off <<= 1) {
        int u = (t >= off) ? psc[t - off] : 0;
        __syncthreads();
        psc[t] += u;
        __syncthreads();
    }
    int excl = psc[t] - pv;
    int base = b << 9;
    int i0 = base + 2 * t, i1 = i0 + 1;
    if (i0 < NN) {
        cursor[i0] = excl;
        float dv = rsqrtf((float)d0 + 1.0f);
        dinv[i0] = dv; xd[i0] = x[i0] * dv;
    }
    if (i1 < NN) {
        cursor[i1] = excl + d0;
        float dv = rsqrtf((float)d1 + 1.0f);
        dinv[i1] = dv; xd[i1] = x[i1] * dv;
    }
    if (t == 255) bsum[b] = psc[255];
    __threadfence();
    __syncthreads();
    if (t == 0) lastflag = (atomicAdd(ticket, 1) == NBIN - 1) ? 1 : 0;
    __syncthreads();
    if (lastflag) {
        __threadfence();
        if (t < 2) stats[t] = 0.0f;
        int v = (t < NBIN) ? bsum[t] : 0;
        psc[t] = v;
        __syncthreads();
        for (int off = 1; off < 256; off <<= 1) {
            int u = (t >= off) ? psc[t - off] : 0;
            __syncthreads();
            psc[t] += u;
            __syncthreads();
        }
        if (t < NBIN) bofs[t] = psc[t] - v;
    }
}

// per-bin fill of eidx (u16) + fused layer-1 scalar propagation + stats
__global__ __launch_bounds__(256) void k_binfill_l1(const int* __restrict__ gcnt,
                                                    const int* __restrict__ bins,
                                                    const int* __restrict__ cursor,
                                                    const int* __restrict__ bofs,
                                                    unsigned short* __restrict__ eidx,
                                                    const float* __restrict__ xd,
                                                    const float* __restrict__ x,
                                                    const float* __restrict__ dinv,
                                                    float* __restrict__ s,
                                                    float* __restrict__ stats) {
    __shared__ int lstart[512], lcur[512];
    __shared__ float ls[256], lq[256];
    int b = blockIdx.x, t = threadIdx.x;
    int base = b << 9;
    int bo = bofs[b];
    for (int l = t; l < 512; l += 256) {
        int i = base + l;
        int st = (i < NN) ? cursor[i] + bo : 0;
        lstart[l] = st; lcur[l] = st;
    }
    __syncthreads();
    int nb = gcnt[b];
    const int* bp = bins + b * BINCAP;
    for (int k = t; k < nb; k += 256) {
        int v = bp[k];
        int pos = atomicAdd(&lcur[v >> 16], 1);
        eidx[pos] = (unsigned short)(v & 0xFFFF);
    }
    __syncthreads();
    float a = 0.0f, q = 0.0f;
    #pragma unroll
    for (int half = 0; half < 2; ++half) {
        int l = t + half * 256;
        int i = base + l;
        if (i < NN) {
            float acc = 0.0f;
            int e0 = lstart[l], e1 = lcur[l];
            for (int k = e0; k < e1; ++k) acc += xd[eidx[k]];
            float di = dinv[i];
            float sv = di * (acc + di * x[i]);
            s[i] = sv;
            a += sv; q += sv * sv;
        }
    }
    ls[t] = a; lq[t] = q;
    __syncthreads();
    for (int st = 128; st > 0; st >>= 1) {
        if (t < st) { ls[t] += ls[t + st]; lq[t] += lq[t + st]; }
        __syncthreads();
    }
    if (t == 0) { atomicAdd(&stats[0], ls[0]); atomicAdd(&stats[1], lq[0]); }
}

// ---------------- fused coeffs + activation + 64x64 matmul (16 nodes/block, fp16 h'=h*dinv) ----------------
__global__ __launch_bounds__(256) void k_mm_l1(const float* __restrict__ s,
                                               const float* __restrict__ stats,
                                               const float* __restrict__ W1,
                                               const float* __restrict__ g1,
                                               const float* __restrict__ bt1,
                                               const float* __restrict__ W,
                                               const float* __restrict__ dinv,
                                               __half* __restrict__ h) {
    __shared__ float Ws[64 * 64];
    __shared__ float xs[4 * 64];
    __shared__ float als[64], cls[64];
    int t = threadIdx.x;
    for (int k = t; k < 64 * 64; k += 256) Ws[k] = W[k];
    if (t < 64) {
        float mean = stats[0] * INV_NN;
        float var  = stats[1] * INV_NN - mean * mean;
        float w = W1[t];
        float rinv = rsqrtf(var * w * w + BN_EPS);
        float a = g1[t] * w * rinv;
        als[t] = a;
        cls[t] = bt1[t] - a * mean;
    }
    int j = t & 63, n = t >> 6;
    #pragma unroll
    for (int it = 0; it < MM_NODES / 4; ++it) {
        int node = blockIdx.x * MM_NODES + it * 4 + n;
        float sv = (node < NN) ? s[node] : 0.0f;
        __syncthreads();
        xs[t] = fmaxf(als[j] * sv + cls[j], 0.0f);
        __syncthreads();
        if (node < NN) {
            float acc = 0.f;
            #pragma unroll
            for (int k = 0; k < 64; ++k) acc += xs[n * 64 + k] * Ws[k * 64 + j];
            h[node * 64 + j] = __float2half(acc * dinv[node]);
        }
    }
}

__global__ __launch_bounds__(256) void k_mm_bn(const float* __restrict__ src,
                                               const float* __restrict__ bnsum,
                                               const float* __restrict__ bnsq,
                                               const float* __restrict__ g,
                                               const float* __restrict__ bt,
                                               const float* __restrict__ W,
                                               const float* __restrict__ dinv,
                                               __half* __restrict__ h) {
    __shared__ float Ws[64 * 64];
    __shared__ float xs[4 * 64];
    __shared__ float scl[64], shf[64];
    int t = threadIdx.x;
    for (int k = t; k < 64 * 64; k += 256) Ws[k] = W[k];
    if (t < 64) {
        float mean = bnsum[t] * INV_NN;
        float var  = bnsq[t] * INV_NN - mean * mean;
        float rinv = rsqrtf(var + BN_EPS);
        float sc = g[t] * rinv;
        scl[t] = sc;
        shf[t] = bt[t] - sc * mean;
    }
    int j = t & 63, n = t >> 6;
    #pragma unroll
    for (int it = 0; it < MM_NODES / 4; ++it) {
        int node = blockIdx.x * MM_NODES + it * 4 + n;
        float v = (node < NN) ? src[node * 64 + j] : 0.0f;
        __syncthreads();
        xs[t] = fmaxf(scl[j] * v + shf[j], 0.0f);
        __syncthreads();
        if (node < NN) {
            float acc = 0.f;
            #pragma unroll
            for (int k = 0; k < 64; ++k) acc += xs[n * 64 + k] * Ws[k * 64 + j];
            h[node * 64 + j] = __float2half(acc * dinv[node]);
        }
    }
}

// ---------------- CSR gather aggregation: 2 nodes per wave (dual edge streams) ----------------
// h is pre-scaled by dinv[src]; agg[c] = dinv[c]*(sum_r h'[r] + h'[c]) + bias
#define ACC8(u, s0, s1, s2, s3, s4, s5, s6, s7) { float2 p_; \
    p_ = __half22float2(*reinterpret_cast<__half2*>(&u.x)); s0 += p_.x; s1 += p_.y; \
    p_ = __half22float2(*reinterpret_cast<__half2*>(&u.y)); s2 += p_.x; s3 += p_.y; \
    p_ = __half22float2(*reinterpret_cast<__half2*>(&u.z)); s4 += p_.x; s5 += p_.y; \
    p_ = __half22float2(*reinterpret_cast<__half2*>(&u.w)); s6 += p_.x; s7 += p_.y; }

__global__ __launch_bounds__(256) void k_gather(const int* __restrict__ cursor,
                                                const int* __restrict__ bofs,
                                                const unsigned short* __restrict__ eidx,
                                                const float* __restrict__ dinv,
                                                const __half* __restrict__ h,
                                                const float* __restrict__ bias,
                                                float* __restrict__ agg,
                                                float* __restrict__ bnsumz,
                                                float* __restrict__ bnsqz) {
    if (blockIdx.x == 0) {
        int tt = threadIdx.x;
        if (tt < 64) bnsumz[tt] = 0.0f;
        else if (tt < 128) bnsqz[tt - 64] = 0.0f;
    }
    int wid = threadIdx.x >> 6;
    int lane = threadIdx.x & 63;
    int eslot = lane >> 3;          // 0..7
    int fb = (lane & 7) << 3;       // feature base in halves
    int n0 = blockIdx.x * 8 + wid * 2;    // NN % 8 == 0 -> n0, n1 always valid
    int n1 = n0 + 1;
    int s0 = cursor[n0] + bofs[n0 >> 9];
    int e0end = cursor[n1] + bofs[n1 >> 9];
    int s1 = e0end;
    int e1end = (n1 < NN - 1) ? cursor[n1 + 1] + bofs[(n1 + 1) >> 9] : NE;
    float a0 = 0.f, a1 = 0.f, a2 = 0.f, a3 = 0.f, a4 = 0.f, a5 = 0.f, a6 = 0.f, a7 = 0.f;
    float b0 = 0.f, b1 = 0.f, b2 = 0.f, b3 = 0.f, b4 = 0.f, b5 = 0.f, b6 = 0.f, b7 = 0.f;
    int e0 = s0 + eslot, e1 = s1 + eslot;
    // dual-stream main loop: 4 independent row loads in flight per lane
    for (; e0 + 8 < e0end && e1 + 8 < e1end; e0 += 16, e1 += 16) {
        int r00 = eidx[e0], r01 = eidx[e0 + 8];
        int r10 = eidx[e1], r11 = eidx[e1 + 8];
        uint4 u0 = *reinterpret_cast<const uint4*>(&h[(r00 << 6) + fb]);
        uint4 u1 = *reinterpret_cast<const uint4*>(&h[(r01 << 6) + fb]);
        uint4 v0 = *reinterpret_cast<const uint4*>(&h[(r10 << 6) + fb]);
        uint4 v1 = *reinterpret_cast<const uint4*>(&h[(r11 << 6) + fb]);
        ACC8(u0, a0, a1, a2, a3, a4, a5, a6, a7);
        ACC8(u1, a0, a1, a2, a3, a4, a5, a6, a7);
        ACC8(v0, b0, b1, b2, b3, b4, b5, b6, b7);
        ACC8(v1, b0, b1, b2, b3, b4, b5, b6, b7);
    }
    for (; e0 < e0end; e0 += 8) {
        int r = eidx[e0];
        uint4 u = *reinterpret_cast<const uint4*>(&h[(r << 6) + fb]);
        ACC8(u, a0, a1, a2, a3, a4, a5, a6, a7);
    }
    for (; e1 < e1end; e1 += 8) {
        int r = eidx[e1];
        uint4 u = *reinterpret_cast<const uint4*>(&h[(r << 6) + fb]);
        ACC8(u, b0, b1, b2, b3, b4, b5, b6, b7);
    }
    // reduce across the 8 slots (lane bits 3,4,5) for both nodes
    #pragma unroll
    for (int d = 8; d <= 32; d <<= 1) {
        a0 += __shfl_xor(a0, d); a1 += __shfl_xor(a1, d);
        a2 += __shfl_xor(a2, d); a3 += __shfl_xor(a3, d);
        a4 += __shfl_xor(a4, d); a5 += __shfl_xor(a5, d);
        a6 += __shfl_xor(a6, d); a7 += __shfl_xor(a7, d);
        b0 += __shfl_xor(b0, d); b1 += __shfl_xor(b1, d);
        b2 += __shfl_xor(b2, d); b3 += __shfl_xor(b3, d);
        b4 += __shfl_xor(b4, d); b5 += __shfl_xor(b5, d);
        b6 += __shfl_xor(b6, d); b7 += __shfl_xor(b7, d);
    }
    int node = -1;
    float s_0, s_1, s_2, s_3, s_4, s_5, s_6, s_7;
    if (eslot == 0) {
        node = n0;
        s_0 = a0; s_1 = a1; s_2 = a2; s_3 = a3; s_4 = a4; s_5 = a5; s_6 = a6; s_7 = a7;
    } else if (eslot == 1) {
        node = n1;
        s_0 = b0; s_1 = b1; s_2 = b2; s_3 = b3; s_4 = b4; s_5 = b5; s_6 = b6; s_7 = b7;
    }
    if (node >= 0) {
        float dc = dinv[node];
        uint4 u = *reinterpret_cast<const uint4*>(&h[(node << 6) + fb]);
        ACC8(u, s_0, s_1, s_2, s_3, s_4, s_5, s_6, s_7);
        const float4 bv0 = *reinterpret_cast<const float4*>(&bias[fb]);
        const float4 bv1 = *reinterpret_cast<const float4*>(&bias[fb + 4]);
        float4 o0, o1;
        o0.x = dc * s_0 + bv0.x; o0.y = dc * s_1 + bv0.y;
        o0.z = dc * s_2 + bv0.z; o0.w = dc * s_3 + bv0.w;
        o1.x = dc * s_4 + bv1.x; o1.y = dc * s_5 + bv1.y;
        o1.z = dc * s_6 + bv1.z; o1.w = dc * s_7 + bv1.w;
        *reinterpret_cast<float4*>(&agg[node * 64 + fb]) = o0;
        *reinterpret_cast<float4*>(&agg[node * 64 + fb + 4]) = o1;
    }
}

// ---------------- batchnorm stats (optionally zeros pooled/cnt) ----------------
__global__ __launch_bounds__(256) void k_bn_stats(const float* __restrict__ agg,
                                                  float* __restrict__ bnsum, float* __restrict__ bnsq,
                                                  float* __restrict__ pooledz, float* __restrict__ cntz) {
    if (pooledz != nullptr && blockIdx.x == 0) {
        for (int k = threadIdx.x; k < 64 * 64; k += 256) pooledz[k] = 0.0f;
        if (threadIdx.x < 64) cntz[threadIdx.x] = 0.0f;
    }
    __shared__ float ls[256], lq[256];
    int j = threadIdx.x & 63, nl = threadIdx.x >> 6;
    float a = 0.f, b = 0.f;
    for (int i = blockIdx.x * 4 + nl; i < NN; i += gridDim.x * 4) {
        float v = agg[i * 64 + j]; a += v; b += v * v;
    }
    ls[threadIdx.x] = a; lq[threadIdx.x] = b; __syncthreads();
    if (threadIdx.x < 128) { ls[threadIdx.x] += ls[threadIdx.x + 128]; lq[threadIdx.x] += lq[threadIdx.x + 128]; }
    __syncthreads();
    if (threadIdx.x < 64) {
        atomicAdd(&bnsum[j], ls[threadIdx.x] + ls[threadIdx.x + 64]);
        atomicAdd(&bnsq[j],  lq[threadIdx.x] + lq[threadIdx.x + 64]);
    }
}

// ---------------- fused BN-finalize + BN + pooling (segmented) ----------------
__global__ __launch_bounds__(256) void k_pool_bn(const float* __restrict__ agg,
                                                 const float* __restrict__ bnsum,
                                                 const float* __restrict__ bnsq,
                                                 const float* __restrict__ g4,
                                                 const float* __restrict__ bt4,
                                                 const int* __restrict__ batch,
                                                 float* __restrict__ pooled,
                                                 float* __restrict__ cnt) {
    const int wpb = 4;
    int wave = blockIdx.x * wpb + (threadIdx.x >> 6);
    int lane = threadIdx.x & 63;
    const int nwaves = gridDim.x * wpb;
    int chunk = (NN + nwaves - 1) / nwaves;
    int i0 = wave * chunk;
    int i1 = i0 + chunk; if (i1 > NN) i1 = NN;
    if (i0 >= NN) return;
    float mean = bnsum[lane] * INV_NN;
    float var  = bnsq[lane] * INV_NN - mean * mean;
    float rinv = rsqrtf(var + BN_EPS);
    float sc = g4[lane] * rinv;
    float sh = bt4[lane] - sc * mean;
    float acc = 0.0f;
    int curb = batch[i0];
    int runlen = 0;
    for (int i = i0; i < i1; ++i) {
        int b = batch[i];
        if (b != curb) {
            atomicAdd(&pooled[curb * 64 + lane], acc);
            if (lane == 0) atomicAdd(&cnt[curb], (float)runlen);
            acc = 0.0f; runlen = 0; curb = b;
        }
        acc += fmaxf(sc * agg[i * 64 + lane] + sh, 0.0f);
        ++runlen;
    }
    atomicAdd(&pooled[curb * 64 + lane], acc);
    if (lane == 0) atomicAdd(&cnt[curb], (float)runlen);
}

__global__ __launch_bounds__(128) void k_fc(const float* __restrict__ pooled, const float* __restrict__ cnt,
                                            const float* __restrict__ fw1, const float* __restrict__ fb1,
                                            const float* __restrict__ fw2, const float* __restrict__ fb2,
                                            float* __restrict__ out) {
    __shared__ float p[64], hsh[128];
    int g = blockIdx.x, t = threadIdx.x;
    if (t < 64) {
        float c = cnt[g]; c = c < 1.f ? 1.f : c;
        p[t] = pooled[g * 64 + t] / c;
    }
    __syncthreads();
    float acc = fb1[t];
    #pragma unroll 8
    for (int k = 0; k < 64; ++k) acc += p[k] * fw1[t * 64 + k];
    hsh[t] = fmaxf(acc, 0.f);
    __syncthreads();
    if (t < 10) {
        float o = fb2[t];
        #pragma unroll 8
        for (int k = 0; k < 128; ++k) o += hsh[k] * fw2[t * 128 + k];
        out[g * 10 + t] = o;
    }
}

// ---------------- launch ----------------
extern "C" void kernel_launch(void* const* d_in, const int* in_sizes, int n_in,
                              void* d_out, int out_size, void* d_ws, size_t ws_size,
                              hipStream_t stream) {
    const float* x   = (const float*)d_in[0];
    const int* ei    = (const int*)d_in[1];
    const int* batch = (const int*)d_in[2];
    const float* W[5]  = {nullptr, (const float*)d_in[3],  (const float*)d_in[7],
                                   (const float*)d_in[11], (const float*)d_in[15]};
    const float* bb[5] = {nullptr, (const float*)d_in[4],  (const float*)d_in[8],
                                   (const float*)d_in[12], (const float*)d_in[16]};
    const float* gg[5] = {nullptr, (const float*)d_in[5],  (const float*)d_in[9],
                                   (const float*)d_in[13], (const float*)d_in[17]};
    const float* bt[5] = {nullptr, (const float*)d_in[6],  (const float*)d_in[10],
                                   (const float*)d_in[14], (const float*)d_in[18]};
    const float* fw1 = (const float*)d_in[19];
    const float* fb1 = (const float*)d_in[20];
    const float* fw2 = (const float*)d_in[21];
    const float* fb2 = (const float*)d_in[22];
    float* out = (float*)d_out;

    const int* row = ei;
    const int* col = ei + NE;

    float* ws = (float*)d_ws;
    int*   cursor  = (int*)ws;                    // N
    unsigned short* eidx = (unsigned short*)(ws + 50000);  // E u16
    float* dinv    = ws + 850000;                 // N
    float* xd      = ws + 900000;                 // N
    int*   bsum    = (int*)(ws + 950000);         // NBIN (inclusive per-bin sums)
    int*   bofs    = (int*)(ws + 950200);         // NBIN (exclusive offsets)
    float* s       = ws + 951000;                 // N
    float* stats   = ws + 1001008;                // 2
    float* bnsum   = ws + 1001072;                // 64
    float* bnsq    = ws + 1001136;                // 64
    float* pooled  = ws + 1001360;                // 64*64
    float* cnt     = ws + 1005456;                // 64
    int*   gcnt    = (int*)(ws + 1056000);        // NBIN + ticket0
    int*   ticket0 = gcnt + NBIN;
    __half* hbuf   = (__half*)(ws + 1100000);     // N*64 halves (bins alias pre-layer2)
    int*   bins    = (int*)(ws + 1100000);        // NBIN*BINCAP ints
    float* aggbuf  = ws + 4300000;                // N*64

    const int B = 256;

    // CSR build (binned) + dinv + xd  (gcnt + ticket zeroed together)
    hipMemsetAsync(gcnt, 0, (NBIN + 1) * sizeof(int), stream);
    k_binscatter<<<SCH_NBLK, B, 0, stream>>>(row, col, gcnt, bins);
    k_binscan<<<NBIN, B, 0, stream>>>(gcnt, bins, x, cursor, bsum, bofs, dinv, xd, ticket0, stats);
    // fill eidx (u16) + layer-1 scalar propagation + stats
    k_binfill_l1<<<NBIN, B, 0, stream>>>(gcnt, bins, cursor, bofs, eidx, xd, x, dinv, s, stats);

    // layer 2
    k_mm_l1<<<MMB_NBLK, B, 0, stream>>>(s, stats, W[1], gg[1], bt[1], W[2], dinv, hbuf);
    k_gather<<<G2_NBLK, B, 0, stream>>>(cursor, bofs, eidx, dinv, hbuf, bb[2], aggbuf, bnsum, bnsq);
    k_bn_stats<<<512, B, 0, stream>>>(aggbuf, bnsum, bnsq, nullptr, nullptr);

    // layers 3,4
    for (int L = 3; L <= 4; ++L) {
        k_mm_bn<<<MMB_NBLK, B, 0, stream>>>(aggbuf, bnsum, bnsq, gg[L - 1], bt[L - 1], W[L], dinv, hbuf);
        k_gather<<<G2_NBLK, B, 0, stream>>>(cursor, bofs, eidx, dinv, hbuf, bb[L], aggbuf, bnsum, bnsq);
        k_bn_stats<<<512, B, 0, stream>>>(aggbuf, bnsum, bnsq,
                                          (L == 4) ? pooled : nullptr, (L == 4) ? cnt : nullptr);
    }

    // fused finalize+BN+pool (segmented) + FC
    k_pool_bn<<<512, B, 0, stream>>>(aggbuf, bnsum, bnsq, gg[4], bt[4], batch, pooled, cnt);
    k_fc<<<NG, 128, 0, stream>>>(pooled, cnt, fw1, fb1, fw2, fb2, out);
}